// Round 2
// baseline (878.373 us; speedup 1.0000x reference)
//
#include <hip/hip_runtime.h>

typedef __attribute__((ext_vector_type(4))) float f32x4;
typedef __attribute__((ext_vector_type(8))) short bf16x8;
typedef __attribute__((ext_vector_type(4))) unsigned short u16x4;

#define NB 4
#define NT 2048
#define NE 1024
#define NH 16
#define ND 64
#define NM (NB*NT)   // 8192 tokens

__device__ inline unsigned short f2bf(float f){
  unsigned int u = __float_as_uint(f);
  return (unsigned short)((u + 0x7fffu + ((u >> 16) & 1u)) >> 16);
}
__device__ inline float bf2f(unsigned short s){
  return __uint_as_float(((unsigned int)s) << 16);
}
__device__ inline f32x4 mfma16(bf16x8 a, bf16x8 b, f32x4 c){
  return __builtin_amdgcn_mfma_f32_16x16x32_bf16(a, b, c, 0, 0, 0);
}
__device__ inline void gload_lds16(const unsigned short* g, unsigned short* l){
  __builtin_amdgcn_global_load_lds(
      (const __attribute__((address_space(1))) void*)g,
      (__attribute__((address_space(3))) void*)l, 16, 0, 0);
}

// ---------- split fp32 x -> bf16 hi/lo ----------
__global__ __launch_bounds__(256) void prep_x_k(const float* __restrict__ x,
    unsigned short* __restrict__ xh, unsigned short* __restrict__ xl, int n4){
  int stride = gridDim.x * 256;
  for (int i = blockIdx.x * 256 + threadIdx.x; i < n4; i += stride){
    f32x4 v = ((const f32x4*)x)[i];
    u16x4 hi, lo;
    #pragma unroll
    for (int j = 0; j < 4; j++){
      hi[j] = f2bf(v[j]);
      lo[j] = f2bf(v[j] - bf2f(hi[j]));
    }
    ((u16x4*)xh)[i] = hi;
    ((u16x4*)xl)[i] = lo;
  }
}

// ---------- w_qkv [K=1024][3072] fp32 -> reordered+transposed hi/lo ----------
// out row n = kk*1024 + h*64 + d  maps to  source col = d*48 + kk*16 + h
__global__ __launch_bounds__(256) void prep_wq_k(const float* __restrict__ w,
    unsigned short* __restrict__ wh, unsigned short* __restrict__ wl){
  int n = blockIdx.x;                       // 0..3071
  int kk = n >> 10, h = (n >> 6) & 15, d = n & 63;
  int col = d * 48 + kk * 16 + h;
  for (int k = threadIdx.x; k < NE; k += 256){
    float v = w[(size_t)k * 3072 + col];
    unsigned short hi = f2bf(v);
    wh[(size_t)n * NE + k] = hi;
    wl[(size_t)n * NE + k] = f2bf(v - bf2f(hi));
  }
}

// ---------- w_out [1024][1024] fp32 -> transposed bf16 [n][k] ----------
__global__ __launch_bounds__(256) void prep_wo_k(const float* __restrict__ w,
    unsigned short* __restrict__ wt){
  int n = blockIdx.x;
  for (int k = threadIdx.x; k < NE; k += 256)
    wt[(size_t)n * NE + k] = f2bf(w[(size_t)k * NE + n]);
}

// ---------- 128x128 bf16 GEMM (B^T layout), optional 3-term fp32-split ----------
// EPI=0: Cf[row*N+col] = acc (fp32 store)
// EPI=1: QK scatter: col = kk*1024+h*64+d -> Qh/Ql or Kh/Kl [b,h,t,d] hi/lo pairs
// EPI=2: V scatter:  col = h*64+d -> Vt [b,h,d,t] bf16
template<int SPLIT, int EPI>
__global__ __launch_bounds__(256) void gemm_k(
    const unsigned short* __restrict__ Ah, const unsigned short* __restrict__ Al,
    const unsigned short* __restrict__ Bh, const unsigned short* __restrict__ Bl,
    float* __restrict__ Cf,
    unsigned short* __restrict__ Qh, unsigned short* __restrict__ Ql,
    unsigned short* __restrict__ Kh, unsigned short* __restrict__ Kl,
    unsigned short* __restrict__ Vt,
    int M, int N, int K){
  __shared__ unsigned short lds[SPLIT ? 4 : 2][128 * 32];
  const int tid = threadIdx.x;
  const int w = tid >> 6, l = tid & 63;
  const int wr = w >> 1, wc = w & 1;
  const int m0 = blockIdx.y * 128, n0 = blockIdx.x * 128;

  f32x4 acc[4][4];
  #pragma unroll
  for (int i = 0; i < 4; i++)
    #pragma unroll
    for (int j = 0; j < 4; j++) acc[i][j] = (f32x4){0.f, 0.f, 0.f, 0.f};

  const int lr = l >> 2;          // row within 16-row chunk
  const int lkb = (l & 3) * 8;    // bf16-element offset along K

  for (int k0 = 0; k0 < K; k0 += 32){
    #pragma unroll
    for (int cc = 0; cc < 2; cc++){
      int c = w + cc * 4;          // chunk 0..7 across 4 waves
      size_t ga = (size_t)(m0 + c * 16 + lr) * K + k0 + lkb;
      size_t gb = (size_t)(n0 + c * 16 + lr) * K + k0 + lkb;
      gload_lds16(Ah + ga, &lds[0][c * 512]);
      gload_lds16(Bh + gb, &lds[1][c * 512]);
      if (SPLIT){
        gload_lds16(Al + ga, &lds[2][c * 512]);
        gload_lds16(Bl + gb, &lds[3][c * 512]);
      }
    }
    __syncthreads();
    bf16x8 ah[4], bh_[4], al[4], bl_[4];
    #pragma unroll
    for (int mi = 0; mi < 4; mi++){
      int o = (wr * 64 + mi * 16 + (l & 15)) * 32 + (l >> 4) * 8;
      ah[mi] = *(bf16x8*)&lds[0][o];
      if (SPLIT) al[mi] = *(bf16x8*)&lds[2][o];
    }
    #pragma unroll
    for (int ni = 0; ni < 4; ni++){
      int o = (wc * 64 + ni * 16 + (l & 15)) * 32 + (l >> 4) * 8;
      bh_[ni] = *(bf16x8*)&lds[1][o];
      if (SPLIT) bl_[ni] = *(bf16x8*)&lds[3][o];
    }
    #pragma unroll
    for (int mi = 0; mi < 4; mi++)
      #pragma unroll
      for (int ni = 0; ni < 4; ni++){
        acc[mi][ni] = mfma16(ah[mi], bh_[ni], acc[mi][ni]);
        if (SPLIT){
          acc[mi][ni] = mfma16(ah[mi], bl_[ni], acc[mi][ni]);
          acc[mi][ni] = mfma16(al[mi], bh_[ni], acc[mi][ni]);
        }
      }
    __syncthreads();
  }

  #pragma unroll
  for (int mi = 0; mi < 4; mi++){
    #pragma unroll
    for (int ni = 0; ni < 4; ni++){
      #pragma unroll
      for (int j = 0; j < 4; j++){
        int row = m0 + wr * 64 + mi * 16 + (l >> 4) * 4 + j;
        int col = n0 + wc * 64 + ni * 16 + (l & 15);
        float v = acc[mi][ni][j];
        if (EPI == 0){
          Cf[(size_t)row * N + col] = v;
        } else if (EPI == 1){
          int kk = col >> 10, h = (col >> 6) & 15, d = col & 63;
          int bb = row >> 11, t = row & (NT - 1);
          size_t off = ((size_t)(bb * NH + h) * NT + t) * ND + d;
          unsigned short hi = f2bf(v);
          unsigned short lo = f2bf(v - bf2f(hi));
          if (kk == 0){ Qh[off] = hi; Ql[off] = lo; }
          else        { Kh[off] = hi; Kl[off] = lo; }
        } else {
          int h = col >> 6, d = col & 63;
          int bb = row >> 11, t = row & (NT - 1);
          Vt[((size_t)(bb * NH + h) * ND + d) * NT + t] = f2bf(v);
        }
      }
    }
  }
}

// ---------- flash attention: S = (Q K^T)*8, softmax, O = P V ----------
// grid (NT/64, NH, NB); 4 waves/block, wave handles 16 q-rows.
__global__ __launch_bounds__(256) void attn_k(
    const unsigned short* __restrict__ Qh, const unsigned short* __restrict__ Ql,
    const unsigned short* __restrict__ Kh, const unsigned short* __restrict__ Kl,
    const unsigned short* __restrict__ Vt, unsigned short* __restrict__ O){
  __shared__ unsigned short plds[4][16 * 40];   // per-wave P tile, padded stride
  const int tid = threadIdx.x;
  const int w = tid >> 6, l = tid & 63;
  const int h = blockIdx.y, b = blockIdx.z;
  const int i0 = blockIdx.x * 64 + w * 16;
  const size_t bh = (size_t)(b * NH + h);

  bf16x8 qh[2], ql[2];
  #pragma unroll
  for (int ks = 0; ks < 2; ks++){
    size_t off = (bh * NT + i0 + (l & 15)) * ND + ks * 32 + (l >> 4) * 8;
    qh[ks] = *(const bf16x8*)(Qh + off);
    ql[ks] = *(const bf16x8*)(Ql + off);
  }

  float mrow[4], lrow[4];
  f32x4 oacc[4];
  #pragma unroll
  for (int j = 0; j < 4; j++){ mrow[j] = -1e30f; lrow[j] = 0.f; }
  #pragma unroll
  for (int ni = 0; ni < 4; ni++) oacc[ni] = (f32x4){0.f, 0.f, 0.f, 0.f};

  for (int j0 = 0; j0 < NT; j0 += 32){
    f32x4 s[2];
    #pragma unroll
    for (int half = 0; half < 2; half++){
      f32x4 a = (f32x4){0.f, 0.f, 0.f, 0.f};
      int jc = j0 + half * 16;
      #pragma unroll
      for (int ks = 0; ks < 2; ks++){
        size_t off = (bh * NT + jc + (l & 15)) * ND + ks * 32 + (l >> 4) * 8;
        bf16x8 khf = *(const bf16x8*)(Kh + off);
        bf16x8 klf = *(const bf16x8*)(Kl + off);
        a = mfma16(qh[ks], khf, a);
        a = mfma16(ql[ks], khf, a);
        a = mfma16(qh[ks], klf, a);
      }
      s[half] = a * 8.0f;   // SCALE = sqrt(64), multiplied per source
    }
    #pragma unroll
    for (int j = 0; j < 4; j++){
      float pm = fmaxf(s[0][j], s[1][j]);
      pm = fmaxf(pm, __shfl_xor(pm, 1));
      pm = fmaxf(pm, __shfl_xor(pm, 2));
      pm = fmaxf(pm, __shfl_xor(pm, 4));
      pm = fmaxf(pm, __shfl_xor(pm, 8));
      float nm = fmaxf(mrow[j], pm);
      float sc = __expf(mrow[j] - nm);
      mrow[j] = nm;
      float p0 = __expf(s[0][j] - nm);
      float p1 = __expf(s[1][j] - nm);
      s[0][j] = p0; s[1][j] = p1;
      float rs = p0 + p1;
      rs += __shfl_xor(rs, 1);
      rs += __shfl_xor(rs, 2);
      rs += __shfl_xor(rs, 4);
      rs += __shfl_xor(rs, 8);
      lrow[j] = lrow[j] * sc + rs;
      #pragma unroll
      for (int ni = 0; ni < 4; ni++) oacc[ni][j] *= sc;
    }
    #pragma unroll
    for (int half = 0; half < 2; half++)
      #pragma unroll
      for (int j = 0; j < 4; j++)
        plds[w][((l >> 4) * 4 + j) * 40 + half * 16 + (l & 15)] = f2bf(s[half][j]);
    asm volatile("s_waitcnt lgkmcnt(0)" ::: "memory");
    bf16x8 pa = *(bf16x8*)&plds[w][(l & 15) * 40 + (l >> 4) * 8];
    #pragma unroll
    for (int ni = 0; ni < 4; ni++){
      size_t voff = (bh * ND + ni * 16 + (l & 15)) * NT + j0 + (l >> 4) * 8;
      bf16x8 vb = *(const bf16x8*)(Vt + voff);
      oacc[ni] = mfma16(pa, vb, oacc[ni]);
    }
  }

  #pragma unroll
  for (int ni = 0; ni < 4; ni++){
    #pragma unroll
    for (int j = 0; j < 4; j++){
      int row = i0 + (l >> 4) * 4 + j;
      int col = h * ND + ni * 16 + (l & 15);
      O[((size_t)b * NT + row) * NE + col] = f2bf(oacc[ni][j] / lrow[j]);
    }
  }
}

extern "C" void kernel_launch(void* const* d_in, const int* in_sizes, int n_in,
                              void* d_out, int out_size, void* d_ws, size_t ws_size,
                              hipStream_t stream){
  const float* x     = (const float*)d_in[0];
  const float* w_qkv = (const float*)d_in[1];
  const float* w_out = (const float*)d_in[2];
  float* out = (float*)d_out;

  char* ws = (char*)d_ws;
  const size_t SZ_X  = (size_t)NM * NE * 2;          // 16.78 MB
  const size_t SZ_WQ = (size_t)3072 * NE * 2;        // 6.29 MB
  const size_t SZ_WO = (size_t)NE * NE * 2;          // 2.10 MB
  const size_t SZ_T  = (size_t)NB * NH * NT * ND * 2;// 16.78 MB

  unsigned short* xh  = (unsigned short*)(ws);                       // later: Obuf
  unsigned short* xl  = (unsigned short*)(ws + SZ_X);                // later: Vt
  unsigned short* wqh = (unsigned short*)(ws + 2 * SZ_X);
  unsigned short* wql = (unsigned short*)(ws + 2 * SZ_X + SZ_WQ);
  unsigned short* wto = (unsigned short*)(ws + 2 * SZ_X + 2 * SZ_WQ);
  unsigned short* Qh  = (unsigned short*)(ws + 2 * SZ_X + 2 * SZ_WQ + SZ_WO);
  unsigned short* Ql  = Qh + (SZ_T / 2);
  unsigned short* Kh  = Qh + 2 * (SZ_T / 2);
  unsigned short* Kl  = Qh + 3 * (SZ_T / 2);
  unsigned short* Vt   = xl;   // xl dead after split GEMM (V uses xh only)
  unsigned short* Obuf = xh;   // xh dead after V GEMM

  const size_t NEED = 2 * SZ_X + 2 * SZ_WQ + SZ_WO + 4 * SZ_T;  // ~110 MB
  if (ws_size < NEED) return;  // distinct signature: out stays zero (absmax ~5.406)

  // 1) preps
  prep_x_k<<<2048, 256, 0, stream>>>(x, xh, xl, NM * NE / 4);
  prep_wq_k<<<3072, 256, 0, stream>>>(w_qkv, wqh, wql);
  prep_wo_k<<<1024, 256, 0, stream>>>(w_out, wto);
  // 2) Q,K projection: 3-term split GEMM over cols [0,2048), scatter hi/lo
  gemm_k<1, 1><<<dim3(2048 / 128, NM / 128), 256, 0, stream>>>(
      xh, xl, wqh, wql, nullptr, Qh, Ql, Kh, Kl, nullptr, NM, 2048, NE);
  // 3) V projection: plain bf16 over cols [2048,3072), scatter transposed
  gemm_k<0, 2><<<dim3(1024 / 128, NM / 128), 256, 0, stream>>>(
      xh, nullptr, wqh + (size_t)2048 * NE, nullptr, nullptr,
      nullptr, nullptr, nullptr, nullptr, Vt, NM, 1024, NE);
  // 4) flash attention
  attn_k<<<dim3(NT / 64, NH, NB), 256, 0, stream>>>(Qh, Ql, Kh, Kl, Vt, Obuf);
  // 5) output projection (fp32 store)
  gemm_k<0, 0><<<dim3(NE / 128, NM / 128), 256, 0, stream>>>(
      Obuf, nullptr, wto, nullptr, out,
      nullptr, nullptr, nullptr, nullptr, nullptr, NM, NE, NE);
}

// Round 4
// 548.017 us; speedup vs baseline: 1.6028x; 1.6028x over previous
//
#include <hip/hip_runtime.h>

typedef __attribute__((ext_vector_type(4))) float f32x4;
typedef __attribute__((ext_vector_type(16))) float f32x16;
typedef __attribute__((ext_vector_type(8))) short bf16x8;
typedef __attribute__((ext_vector_type(4))) unsigned short u16x4;

#define NB 4
#define NT 2048
#define NE 1024
#define NH 16
#define ND 64
#define NM (NB*NT)   // 8192 tokens

__device__ inline unsigned short f2bf(float f){
  unsigned int u = __float_as_uint(f);
  return (unsigned short)((u + 0x7fffu + ((u >> 16) & 1u)) >> 16);
}
__device__ inline float bf2f(unsigned short s){
  return __uint_as_float(((unsigned int)s) << 16);
}
__device__ inline f32x4 mfma16(bf16x8 a, bf16x8 b, f32x4 c){
  return __builtin_amdgcn_mfma_f32_16x16x32_bf16(a, b, c, 0, 0, 0);
}
__device__ inline f32x16 mfma32(bf16x8 a, bf16x8 b, f32x16 c){
  return __builtin_amdgcn_mfma_f32_32x32x16_bf16(a, b, c, 0, 0, 0);
}
__device__ inline void gload_lds16(const unsigned short* g, unsigned short* l){
  __builtin_amdgcn_global_load_lds(
      (const __attribute__((address_space(1))) void*)g,
      (__attribute__((address_space(3))) void*)l, 16, 0, 0);
}

// ---------- split fp32 x -> bf16 hi/lo ----------
__global__ __launch_bounds__(256) void prep_x_k(const float* __restrict__ x,
    unsigned short* __restrict__ xh, unsigned short* __restrict__ xl, int n4){
  int stride = gridDim.x * 256;
  for (int i = blockIdx.x * 256 + threadIdx.x; i < n4; i += stride){
    f32x4 v = ((const f32x4*)x)[i];
    u16x4 hi, lo;
    #pragma unroll
    for (int j = 0; j < 4; j++){
      hi[j] = f2bf(v[j]);
      lo[j] = f2bf(v[j] - bf2f(hi[j]));
    }
    ((u16x4*)xh)[i] = hi;
    ((u16x4*)xl)[i] = lo;
  }
}

// ---------- w_qkv [K=1024][3072] fp32 -> reordered+transposed hi/lo ----------
// out row n = kk*1024 + h*64 + d  maps to  source col = d*48 + kk*16 + h
__global__ __launch_bounds__(256) void prep_wq_k(const float* __restrict__ w,
    unsigned short* __restrict__ wh, unsigned short* __restrict__ wl){
  int n = blockIdx.x;                       // 0..3071
  int kk = n >> 10, h = (n >> 6) & 15, d = n & 63;
  int col = d * 48 + kk * 16 + h;
  for (int k = threadIdx.x; k < NE; k += 256){
    float v = w[(size_t)k * 3072 + col];
    unsigned short hi = f2bf(v);
    wh[(size_t)n * NE + k] = hi;
    wl[(size_t)n * NE + k] = f2bf(v - bf2f(hi));
  }
}

// ---------- w_out [1024][1024] fp32 -> transposed bf16 [n][k] ----------
__global__ __launch_bounds__(256) void prep_wo_k(const float* __restrict__ w,
    unsigned short* __restrict__ wt){
  int n = blockIdx.x;
  for (int k = threadIdx.x; k < NE; k += 256)
    wt[(size_t)n * NE + k] = f2bf(w[(size_t)k * NE + n]);
}

// ---------- 128x128 bf16 GEMM (B^T layout), optional 3-term fp32-split ----------
template<int SPLIT, int EPI>
__global__ __launch_bounds__(256) void gemm_k(
    const unsigned short* __restrict__ Ah, const unsigned short* __restrict__ Al,
    const unsigned short* __restrict__ Bh, const unsigned short* __restrict__ Bl,
    float* __restrict__ Cf,
    unsigned short* __restrict__ Qh, unsigned short* __restrict__ Ql,
    unsigned short* __restrict__ Kh, unsigned short* __restrict__ Kl,
    unsigned short* __restrict__ Vt,
    int M, int N, int K){
  __shared__ unsigned short lds[SPLIT ? 4 : 2][128 * 32];
  const int tid = threadIdx.x;
  const int w = tid >> 6, l = tid & 63;
  const int wr = w >> 1, wc = w & 1;
  const int m0 = blockIdx.y * 128, n0 = blockIdx.x * 128;

  f32x4 acc[4][4];
  #pragma unroll
  for (int i = 0; i < 4; i++)
    #pragma unroll
    for (int j = 0; j < 4; j++) acc[i][j] = (f32x4){0.f, 0.f, 0.f, 0.f};

  const int lr = l >> 2;
  const int lkb = (l & 3) * 8;

  for (int k0 = 0; k0 < K; k0 += 32){
    #pragma unroll
    for (int cc = 0; cc < 2; cc++){
      int c = w + cc * 4;
      size_t ga = (size_t)(m0 + c * 16 + lr) * K + k0 + lkb;
      size_t gb = (size_t)(n0 + c * 16 + lr) * K + k0 + lkb;
      gload_lds16(Ah + ga, &lds[0][c * 512]);
      gload_lds16(Bh + gb, &lds[1][c * 512]);
      if (SPLIT){
        gload_lds16(Al + ga, &lds[2][c * 512]);
        gload_lds16(Bl + gb, &lds[3][c * 512]);
      }
    }
    __syncthreads();
    bf16x8 ah[4], bh_[4], al[4], bl_[4];
    #pragma unroll
    for (int mi = 0; mi < 4; mi++){
      int o = (wr * 64 + mi * 16 + (l & 15)) * 32 + (l >> 4) * 8;
      ah[mi] = *(bf16x8*)&lds[0][o];
      if (SPLIT) al[mi] = *(bf16x8*)&lds[2][o];
    }
    #pragma unroll
    for (int ni = 0; ni < 4; ni++){
      int o = (wc * 64 + ni * 16 + (l & 15)) * 32 + (l >> 4) * 8;
      bh_[ni] = *(bf16x8*)&lds[1][o];
      if (SPLIT) bl_[ni] = *(bf16x8*)&lds[3][o];
    }
    #pragma unroll
    for (int mi = 0; mi < 4; mi++)
      #pragma unroll
      for (int ni = 0; ni < 4; ni++){
        acc[mi][ni] = mfma16(ah[mi], bh_[ni], acc[mi][ni]);
        if (SPLIT){
          acc[mi][ni] = mfma16(ah[mi], bl_[ni], acc[mi][ni]);
          acc[mi][ni] = mfma16(al[mi], bh_[ni], acc[mi][ni]);
        }
      }
    __syncthreads();
  }

  #pragma unroll
  for (int mi = 0; mi < 4; mi++){
    #pragma unroll
    for (int ni = 0; ni < 4; ni++){
      #pragma unroll
      for (int j = 0; j < 4; j++){
        int row = m0 + wr * 64 + mi * 16 + (l >> 4) * 4 + j;
        int col = n0 + wc * 64 + ni * 16 + (l & 15);
        float v = acc[mi][ni][j];
        if (EPI == 0){
          Cf[(size_t)row * N + col] = v;
        } else if (EPI == 1){
          int kk = col >> 10, h = (col >> 6) & 15, d = col & 63;
          int bb = row >> 11, t = row & (NT - 1);
          size_t off = ((size_t)(bb * NH + h) * NT + t) * ND + d;
          unsigned short hi = f2bf(v);
          unsigned short lo = f2bf(v - bf2f(hi));
          if (kk == 0){ Qh[off] = hi; Ql[off] = lo; }
          else        { Kh[off] = hi; Kl[off] = lo; }
        } else {
          int h = col >> 6, d = col & 63;
          int bb = row >> 11, t = row & (NT - 1);
          Vt[((size_t)(bb * NH + h) * ND + d) * NT + t] = f2bf(v);
        }
      }
    }
  }
}

// ---------- flash attention, 32x32 MFMA, swapped QK^T, in-register softmax ----
// grid (NT/128, NH, NB); 4 waves/block, each wave owns 32 q-rows.
// S-tile: mfma32(A=K, B=Q) -> lane l holds S[kt][q] with q = l&31,
// kt = (r&3) + 8*(r>>2) + 4*(l>>5).  Softmax stats indexed by q=lane&31;
// O rows indexed by crow(r,hi) -> rescale/normalize must __shfl per row.
__global__ __launch_bounds__(256, 3) void attn_k(
    const unsigned short* __restrict__ Qh, const unsigned short* __restrict__ Ql,
    const unsigned short* __restrict__ Kh, const unsigned short* __restrict__ Kl,
    const unsigned short* __restrict__ Vt, unsigned short* __restrict__ O){
  const int tid = threadIdx.x;
  const int w = tid >> 6, l = tid & 63;
  const int qi = l & 31, hi = l >> 5;
  const int h = blockIdx.y, b = blockIdx.z;
  const int i0 = blockIdx.x * 128 + w * 32;
  const size_t bh = (size_t)(b * NH + h);

  bf16x8 qh[4], qlo[4];
  {
    const unsigned short* qb  = Qh + (bh * NT + i0 + qi) * ND + hi * 8;
    const unsigned short* qlb = Ql + (bh * NT + i0 + qi) * ND + hi * 8;
    #pragma unroll
    for (int c = 0; c < 4; c++){
      qh[c]  = *(const bf16x8*)(qb + c * 16);
      qlo[c] = *(const bf16x8*)(qlb + c * 16);
    }
  }

  f32x16 o0, o1;
  #pragma unroll
  for (int r = 0; r < 16; r++){ o0[r] = 0.f; o1[r] = 0.f; }
  float mrun = -3.0e38f, lrun = 0.f;

  const unsigned short* kb0 = Kh + (bh * NT + qi) * ND + hi * 8;
  const unsigned short* kl0 = Kl + (bh * NT + qi) * ND + hi * 8;
  const unsigned short* vb0 = Vt + (bh * ND + qi) * NT + hi * 8;

  for (int j0 = 0; j0 < NT; j0 += 32){
    bf16x8 kh[4], kl[4];
    #pragma unroll
    for (int c = 0; c < 4; c++){
      kh[c] = *(const bf16x8*)(kb0 + (size_t)j0 * ND + c * 16);
      kl[c] = *(const bf16x8*)(kl0 + (size_t)j0 * ND + c * 16);
    }
    bf16x8 vb[2][2];
    #pragma unroll
    for (int dt = 0; dt < 2; dt++)
      #pragma unroll
      for (int k0 = 0; k0 < 2; k0++)
        vb[dt][k0] = *(const bf16x8*)(vb0 + (size_t)dt * 32 * NT + j0 + k0 * 16);

    // 3-term split QK^T
    f32x16 s;
    #pragma unroll
    for (int r = 0; r < 16; r++) s[r] = 0.f;
    #pragma unroll
    for (int c = 0; c < 4; c++) s = mfma32(kh[c], qh[c], s);
    #pragma unroll
    for (int c = 0; c < 4; c++) s = mfma32(kl[c], qh[c], s);
    #pragma unroll
    for (int c = 0; c < 4; c++) s = mfma32(kh[c], qlo[c], s);

    // online softmax, logits L = s*8; stats per q = lane&31
    float pm = s[0];
    #pragma unroll
    for (int r = 1; r < 16; r++) pm = fmaxf(pm, s[r]);
    pm = fmaxf(pm, __shfl_xor(pm, 32));
    float Lm = pm * 8.0f;
    if (!__all(Lm <= mrun + 8.0f)){      // defer-max (T13), THR=8
      float nm = fmaxf(mrun, Lm);
      float sc = __expf(mrun - nm);      // per-lane, indexed by q=lane&31
      mrun = nm;
      lrun *= sc;
      #pragma unroll
      for (int r = 0; r < 16; r++){      // O row = crow(r,hi): gather row's sc
        int mrow = (r & 3) + 8 * (r >> 2) + 4 * hi;
        float scr = __shfl(sc, mrow);
        o0[r] *= scr;
        o1[r] *= scr;
      }
    }
    float p[16], rs = 0.f;
    #pragma unroll
    for (int r = 0; r < 16; r++){
      p[r] = __expf(fmaf(s[r], 8.0f, -mrun));
      rs += p[r];
    }
    rs += __shfl_xor(rs, 32);
    lrun += rs;

    // P -> bf16 A-fragments via lane<->lane+32 exchange (no LDS)
    unsigned int pk[8];
    #pragma unroll
    for (int i = 0; i < 8; i++)
      pk[i] = (unsigned int)f2bf(p[2 * i]) | ((unsigned int)f2bf(p[2 * i + 1]) << 16);
    unsigned int sw[8];
    #pragma unroll
    for (int i = 0; i < 8; i++) sw[i] = __shfl_xor(pk[i], 32);

    union { unsigned int u[4]; bf16x8 v; } pa0, pa1;
    pa0.u[0] = hi ? sw[2] : pk[0];
    pa0.u[1] = hi ? sw[3] : pk[1];
    pa0.u[2] = hi ? pk[2] : sw[0];
    pa0.u[3] = hi ? pk[3] : sw[1];
    pa1.u[0] = hi ? sw[6] : pk[4];
    pa1.u[1] = hi ? sw[7] : pk[5];
    pa1.u[2] = hi ? pk[6] : sw[4];
    pa1.u[3] = hi ? pk[7] : sw[5];

    o0 = mfma32(pa0.v, vb[0][0], o0);
    o0 = mfma32(pa1.v, vb[0][1], o0);
    o1 = mfma32(pa0.v, vb[1][0], o1);
    o1 = mfma32(pa1.v, vb[1][1], o1);
  }

  // normalize (lrun for row mrow lives in lane mrow) and store
  float rl = 1.0f / lrun;
  #pragma unroll
  for (int r = 0; r < 16; r++){
    int mrow = (r & 3) + 8 * (r >> 2) + 4 * hi;
    float f = __shfl(rl, mrow);
    size_t base = ((size_t)b * NT + i0 + mrow) * NE + h * ND + qi;
    O[base]      = f2bf(o0[r] * f);
    O[base + 32] = f2bf(o1[r] * f);
  }
}

extern "C" void kernel_launch(void* const* d_in, const int* in_sizes, int n_in,
                              void* d_out, int out_size, void* d_ws, size_t ws_size,
                              hipStream_t stream){
  const float* x     = (const float*)d_in[0];
  const float* w_qkv = (const float*)d_in[1];
  const float* w_out = (const float*)d_in[2];
  float* out = (float*)d_out;

  char* ws = (char*)d_ws;
  const size_t SZ_X  = (size_t)NM * NE * 2;
  const size_t SZ_WQ = (size_t)3072 * NE * 2;
  const size_t SZ_WO = (size_t)NE * NE * 2;
  const size_t SZ_T  = (size_t)NB * NH * NT * ND * 2;

  unsigned short* xh  = (unsigned short*)(ws);
  unsigned short* xl  = (unsigned short*)(ws + SZ_X);
  unsigned short* wqh = (unsigned short*)(ws + 2 * SZ_X);
  unsigned short* wql = (unsigned short*)(ws + 2 * SZ_X + SZ_WQ);
  unsigned short* wto = (unsigned short*)(ws + 2 * SZ_X + 2 * SZ_WQ);
  unsigned short* Qh  = (unsigned short*)(ws + 2 * SZ_X + 2 * SZ_WQ + SZ_WO);
  unsigned short* Ql  = Qh + (SZ_T / 2);
  unsigned short* Kh  = Qh + 2 * (SZ_T / 2);
  unsigned short* Kl  = Qh + 3 * (SZ_T / 2);
  unsigned short* Vt   = xl;   // xl dead after split GEMM
  unsigned short* Obuf = xh;   // xh dead after V GEMM

  const size_t NEED = 2 * SZ_X + 2 * SZ_WQ + SZ_WO + 4 * SZ_T;
  if (ws_size < NEED) return;

  prep_x_k<<<2048, 256, 0, stream>>>(x, xh, xl, NM * NE / 4);
  prep_wq_k<<<3072, 256, 0, stream>>>(w_qkv, wqh, wql);
  prep_wo_k<<<1024, 256, 0, stream>>>(w_out, wto);
  gemm_k<1, 1><<<dim3(2048 / 128, NM / 128), 256, 0, stream>>>(
      xh, xl, wqh, wql, nullptr, Qh, Ql, Kh, Kl, nullptr, NM, 2048, NE);
  gemm_k<0, 2><<<dim3(1024 / 128, NM / 128), 256, 0, stream>>>(
      xh, nullptr, wqh + (size_t)2048 * NE, nullptr, nullptr,
      nullptr, nullptr, nullptr, nullptr, Vt, NM, 1024, NE);
  attn_k<<<dim3(NT / 128, NH, NB), 256, 0, stream>>>(Qh, Ql, Kh, Kl, Vt, Obuf);
  gemm_k<0, 0><<<dim3(NE / 128, NM / 128), 256, 0, stream>>>(
      Obuf, nullptr, wto, nullptr, out,
      nullptr, nullptr, nullptr, nullptr, nullptr, NM, NE, NE);
}